// Round 1
// 1452.115 us; speedup vs baseline: 1.0508x; 1.0508x over previous
//
#include <hip/hip_runtime.h>
#include <cstdint>
#include <cstddef>

#define B_TOT 2048
#define T_TOT 50
#define NIN   620
#define NH    620
#define NCLS  11

// OpenBLAS sgemm K-panel size (SGEMM_DEFAULT_Q). Per-element arithmetic:
// C = fl( fl(chain k<KC) + fl(chain k>=KC) ), each chain single-accumulator
// ascending-k fmaf. THIS RECIPE IS BITWISE-VERIFIED (R4, absmax=0) — do not
// change summation order, only scheduling.
#define KC 384

// GEMM tiling: 128x128 block tile, 8x8 microtile, KB=32.
// Panel split handled by dumping chain-A accs raw to Z at k0==KC-KB, then
// reusing the same 64 acc regs for chain B; epilogue merges with one
// __fadd_rn (bitwise same as dual-acc R4 version).
//
// R5 lane remap (bank-conflict fix; math/order untouched):
//  * b-fragment: lane owns cols {tx*4+j} u {64+tx*4+j} -> the two
//    ds_read_b128 hit 16B-stride chunks across lanes = uniform 2-way (free)
//    instead of 32B-stride = 4-way.
//  * staging: task -> row=(task>>2)&127, kl=(task>>9)*16+(task&3)*4 ->
//    write banks (l&1)*16 + 4q + (l>>2) + r0 cover all 32 banks exactly
//    twice = uniform 2-way (free) instead of 16 banks 4-way. Global side
//    stays coalesced: 4 lanes x 16B = 64B contiguous per row.
#define BM 128
#define BN 128
#define KB 32   // KC % KB == 0 -> split is tile-aligned

__global__ __launch_bounds__(256, 4)
void gemm_relu_kernel(const float* __restrict__ X,
                      const float* __restrict__ W1,
                      float* __restrict__ Z,
                      int t0, int ct)
{
    __shared__ float As[KB][BM + 4];
    __shared__ float Bs[KB][BN + 4];

    const int tid = threadIdx.x;
    const int n0 = blockIdx.x * BN;
    const int m0 = blockIdx.y * BM;
    const int tx = tid & 15;   // n direction: cols tx*4..tx*4+3 and 64+tx*4..
    const int ty = tid >> 4;   // m direction, 8 rows each

    // Staging: tile = 128 rows x 8 k-quads = 1024 float4 tasks, 4 per thread.
    // Per wave: 16 consecutive rows x 4 low k-quads (64B contiguous/row).
    size_t a_off[4];
    size_t b_off[4];
    int    s_row[4], s_kl[4], b_ok[4];
#pragma unroll
    for (int it = 0; it < 4; ++it) {
        int task = tid + it * 256;
        int row  = (task >> 2) & 127;                  // 0..127
        int kl   = (task >> 9) * 16 + (task & 3) * 4;  // 0..28
        s_row[it] = row;
        s_kl[it]  = kl;
        int m  = m0 + row;
        int bb = m / ct;
        int dt = m - bb * ct;
        a_off[it] = ((size_t)bb * T_TOT + (size_t)(t0 + dt)) * (size_t)NIN + kl;
        int n = n0 + row;
        b_off[it] = (size_t)n * NIN + kl;
        b_ok[it]  = (n < NH);
    }

    float acc[8][8];
#pragma unroll
    for (int i = 0; i < 8; ++i)
#pragma unroll
        for (int j = 0; j < 8; ++j) acc[i][j] = 0.0f;

    const int zc0 = n0 + tx * 4;        // cols for acc[i][0..3]
    const int zc1 = n0 + 64 + tx * 4;   // cols for acc[i][4..7]

    for (int k0 = 0; k0 < NIN; k0 += KB) {
        // ---- stage (k-major transposed; zero-fill tail: fma(0,0,c)=c exact)
#pragma unroll
        for (int it = 0; it < 4; ++it) {
            int k = k0 + s_kl[it];
            float4 av = make_float4(0.f, 0.f, 0.f, 0.f);
            if (k < NIN) av = *(const float4*)(X + a_off[it] + k0);
            As[s_kl[it] + 0][s_row[it]] = av.x;
            As[s_kl[it] + 1][s_row[it]] = av.y;
            As[s_kl[it] + 2][s_row[it]] = av.z;
            As[s_kl[it] + 3][s_row[it]] = av.w;
            float4 bv = make_float4(0.f, 0.f, 0.f, 0.f);
            if (b_ok[it] && k < NIN) bv = *(const float4*)(W1 + b_off[it] + k0);
            Bs[s_kl[it] + 0][s_row[it]] = bv.x;
            Bs[s_kl[it] + 1][s_row[it]] = bv.y;
            Bs[s_kl[it] + 2][s_row[it]] = bv.z;
            Bs[s_kl[it] + 3][s_row[it]] = bv.w;
        }
        __syncthreads();

        // ---- compute: ascending k, 64 fma per kk
#pragma unroll 8
        for (int kk = 0; kk < KB; ++kk) {
            float a[8], b[8];
            *(float4*)&a[0] = *(const float4*)&As[kk][ty * 8];
            *(float4*)&a[4] = *(const float4*)&As[kk][ty * 8 + 4];
            *(float4*)&b[0] = *(const float4*)&Bs[kk][tx * 4];
            *(float4*)&b[4] = *(const float4*)&Bs[kk][64 + tx * 4];
#pragma unroll
            for (int i = 0; i < 8; ++i)
#pragma unroll
                for (int j = 0; j < 8; ++j)
                    acc[i][j] = fmaf(a[i], b[j], acc[i][j]);
        }
        __syncthreads();

        // ---- panel boundary: dump chain-A raw to Z, zero accs (uniform branch)
        if (k0 + KB == KC) {
#pragma unroll
            for (int i = 0; i < 8; ++i) {
                float* zr = Z + (size_t)(m0 + ty * 8 + i) * NH;
                if (zc0 < NH)
                    *(float4*)(zr + zc0) = make_float4(acc[i][0], acc[i][1],
                                                       acc[i][2], acc[i][3]);
                if (zc1 < NH)
                    *(float4*)(zr + zc1) = make_float4(acc[i][4], acc[i][5],
                                                       acc[i][6], acc[i][7]);
            }
#pragma unroll
            for (int i = 0; i < 8; ++i)
#pragma unroll
                for (int j = 0; j < 8; ++j) acc[i][j] = 0.0f;
            // stores drain at the next iteration's __syncthreads (vmcnt(0));
            // same-thread readback in epilogue is L2-coherent.
        }
    }

    // ---- epilogue: merge panels (one rounded add), relu, store
#pragma unroll
    for (int i = 0; i < 8; ++i) {
        float* zr = Z + (size_t)(m0 + ty * 8 + i) * NH;
        if (zc0 < NH) {
            float4 p = *(const float4*)(zr + zc0);   // chain A
            float4 v;
            v.x = fmaxf(__fadd_rn(p.x, acc[i][0]), 0.0f);
            v.y = fmaxf(__fadd_rn(p.y, acc[i][1]), 0.0f);
            v.z = fmaxf(__fadd_rn(p.z, acc[i][2]), 0.0f);
            v.w = fmaxf(__fadd_rn(p.w, acc[i][3]), 0.0f);
            *(float4*)(zr + zc0) = v;
        }
        if (zc1 < NH) {
            float4 p = *(const float4*)(zr + zc1);   // chain A
            float4 v;
            v.x = fmaxf(__fadd_rn(p.x, acc[i][4]), 0.0f);
            v.y = fmaxf(__fadd_rn(p.y, acc[i][5]), 0.0f);
            v.z = fmaxf(__fadd_rn(p.z, acc[i][6]), 0.0f);
            v.w = fmaxf(__fadd_rn(p.w, acc[i][7]), 0.0f);
            *(float4*)(zr + zc1) = v;
        }
    }
}

// ---------------------------------------------------------------------------
// Phase B: recurrence, fp32, np-bitwise. One wave per b; spikes in LDS;
// layer-2 = two ascending-k chains split at KC, run CONCURRENTLY on lanes
// c (panel A) and c+32 (panel B), merged via shuffle + one __fadd_rn.
// ---------------------------------------------------------------------------
#define NWAVE 4
__global__ __launch_bounds__(256)
void snn_kernel(const float* __restrict__ Z,
                const float* __restrict__ W2,
                float* __restrict__ state,
                float* __restrict__ out,
                int t0, int ct)
{
    __shared__ float W2s[NCLS][NH];     // 27.3 KB
    __shared__ float Ss[NWAVE][NH];     // 9.9 KB

    const int tid = threadIdx.x;
    for (int i = tid; i < NCLS * NH; i += 256)
        ((float*)W2s)[i] = W2[i];
    __syncthreads();

    const int lane = tid & 63;
    const int wv   = tid >> 6;
    const int b    = blockIdx.x * NWAVE + wv;

    float* st_h1m = state;
    float* st_h1s = state + (size_t)B_TOT * NH;
    float* st_h2m = state + (size_t)2 * B_TOT * NH;
    float* st_h2s = st_h2m + (size_t)B_TOT * NCLS;
    float* st_acc = st_h2s + (size_t)B_TOT * NCLS;

    float h1m[10], h1s[10];
    float h2m = 0.f, h2s = 0.f, acc = 0.f;   // lane<11 owns class c=lane

    if (t0 == 0) {
#pragma unroll
        for (int i = 0; i < 10; ++i) { h1m[i] = 0.f; h1s[i] = 0.f; }
    } else {
#pragma unroll
        for (int i = 0; i < 10; ++i) {
            int k = i * 64 + lane;
            if (k < NH) {
                h1m[i] = st_h1m[(size_t)b * NH + k];
                h1s[i] = st_h1s[(size_t)b * NH + k];
            } else { h1m[i] = 0.f; h1s[i] = 0.f; }
        }
        if (lane < NCLS) {
            h2m = st_h2m[(size_t)b * NCLS + lane];
            h2s = st_h2s[(size_t)b * NCLS + lane];
            acc = st_acc[(size_t)b * NCLS + lane];
        }
    }

    const int cls   = lane & 31;
    const int qbase = (lane < 32) ? 0 : (KC / 4);                 // 0 / 96
    const int qcnt  = (lane < 32) ? (KC / 4) : ((NH - KC) / 4);   // 96 / 59

    for (int dt = 0; dt < ct; ++dt) {
        const float* z = Z + ((size_t)b * ct + dt) * NH;

        // layer-1 membrane (np op order, each op separately rounded)
#pragma unroll
        for (int i = 0; i < 10; ++i) {
            int k = i * 64 + lane;
            if (k < NH) {
                float dec = __fmul_rn(__fmul_rn(h1m[i], 0.2f), (1.0f - h1s[i]));
                float m = __fadd_rn(dec, z[k]);
                float s = (m > 0.5f) ? 1.0f : 0.0f;
                h1m[i] = m; h1s[i] = s;
                Ss[wv][k] = s;
            }
        }
        __syncthreads();

        // layer-2: both panel chains in parallel (lane c: A, lane c+32: B)
        float csum = 0.0f;
        if (cls < NCLS) {
            const float4* w4 = (const float4*)&W2s[cls][0] + qbase;
            const float4* s4 = (const float4*)&Ss[wv][0] + qbase;
            for (int q = 0; q < qcnt; ++q) {      // ascending k within panel
                float4 w = w4[q];
                float4 s = s4[q];
                csum = fmaf(s.x, w.x, csum);
                csum = fmaf(s.y, w.y, csum);
                csum = fmaf(s.z, w.z, csum);
                csum = fmaf(s.w, w.w, csum);
            }
        }
        float csumB = __shfl_xor(csum, 32, 64);   // lane c receives panel B
        if (lane < NCLS) {
            float ctot = __fadd_rn(csum, csumB);  // single panel-merge add
            float dec = __fmul_rn(__fmul_rn(h2m, 0.2f), (1.0f - h2s));
            float m = __fadd_rn(dec, fmaxf(ctot, 0.0f));
            float s = (m > 0.5f) ? 1.0f : 0.0f;
            h2m = m; h2s = s;
            acc = __fadd_rn(acc, s);              // small-int adds, exact
        }
        __syncthreads();   // protect Ss against next-iteration overwrite
    }

    if (t0 + ct >= T_TOT) {
        if (lane < NCLS)
            out[(size_t)b * NCLS + lane] = __fdiv_rn(acc, 50.0f);
    } else {
#pragma unroll
        for (int i = 0; i < 10; ++i) {
            int k = i * 64 + lane;
            if (k < NH) {
                st_h1m[(size_t)b * NH + k] = h1m[i];
                st_h1s[(size_t)b * NH + k] = h1s[i];
            }
        }
        if (lane < NCLS) {
            st_h2m[(size_t)b * NCLS + lane] = h2m;
            st_h2s[(size_t)b * NCLS + lane] = h2s;
            st_acc[(size_t)b * NCLS + lane] = acc;
        }
    }
}

// ---------------------------------------------------------------------------
extern "C" void kernel_launch(void* const* d_in, const int* in_sizes, int n_in,
                              void* d_out, int out_size, void* d_ws, size_t ws_size,
                              hipStream_t stream)
{
    const float* X  = (const float*)d_in[0];   // (2048, 50, 620) fp32
    const float* W1 = (const float*)d_in[1];   // (620, 620)
    const float* W2 = (const float*)d_in[2];   // (11, 620)
    float* out = (float*)d_out;                // (2048, 11) fp32

    const size_t state_floats = (size_t)2 * B_TOT * NH + (size_t)3 * B_TOT * NCLS;
    const size_t state_bytes  = state_floats * sizeof(float);
    const size_t bytes_per_t  = (size_t)B_TOT * NH * sizeof(float);

    size_t avail = (ws_size > state_bytes) ? (ws_size - state_bytes) : 0;
    int chunkT = (int)(avail / bytes_per_t);
    if (chunkT > T_TOT) chunkT = T_TOT;
    if (chunkT < 1) chunkT = 1;   // requires ws_size >= ~15.6 MB

    float* state = (float*)d_ws;
    float* Zbuf  = state + state_floats;

    for (int t0 = 0; t0 < T_TOT; t0 += chunkT) {
        int ct = (T_TOT - t0 < chunkT) ? (T_TOT - t0) : chunkT;
        dim3 ggrid((NH + BN - 1) / BN, (B_TOT * ct) / BM);
        gemm_relu_kernel<<<ggrid, 256, 0, stream>>>(X, W1, Zbuf, t0, ct);
        snn_kernel<<<dim3(B_TOT / NWAVE), 256, 0, stream>>>(Zbuf, W2, state, out, t0, ct);
    }
}